// Round 15
// baseline (584.012 us; speedup 1.0000x reference)
//
#include <hip/hip_runtime.h>

// SpikingMoEFFN: top-2-of-8 spiking router + per-expert SpikingSwiGLU.
// Grouped-GEMM implementation. Spike decisions emulate the np reference's
// f32 BLAS accumulation (sgemm KC=384 panels; verified round 3) via bf16x3
// MFMA screen + f64/exact-emulation patch.
// Round 15: round-14 occupancy design (64-row tiles, 32/16 KB LDS,
// launch_bounds(256,4)) with the stage-B LDS read-offset bug fixed
// (W_down region starts at ushort 4096 in the 16 KB buffer, not 8192 —
// round 14 read past the written region -> NaN).

#define D_MODEL 1024
#define HID     2816
#define NEXP    8
#define NTOK    2048
#define NPAIR   4096
#define TM      64
#define FLAGCAP  32768
#define KC      384
#define BAND    3e-4f
#define INNER   2e-5
#define NBA     22          // HID/128 n-panels (stage A)
#define NBB     16          // D_MODEL/64 n-panels (stage B)
#define AMAX    256         // per-XCD slot cap, stage A
#define BMAX    160         // per-XCD slot cap, stage B

typedef short s8v __attribute__((ext_vector_type(8)));
typedef float f4v __attribute__((ext_vector_type(4)));

__device__ __forceinline__ unsigned short f2bf(float f) {
  unsigned u = __float_as_uint(f);
  u += 0x7FFFu + ((u >> 16) & 1u);   // RTNE
  return (unsigned short)(u >> 16);
}
__device__ __forceinline__ float bf2f(unsigned short s) {
  return __uint_as_float(((unsigned)s) << 16);
}

// async global->LDS, 16B per lane; LDS dest = wave-uniform base + lane*16
__device__ __forceinline__ void gld16(const unsigned short* g, unsigned short* l) {
  __builtin_amdgcn_global_load_lds(
      (const __attribute__((address_space(1))) void*)g,
      (__attribute__((address_space(3))) void*)l, 16, 0, 0);
}

// Exact np-f32 gate emulation: seq FMA within KC=384 panels, panels added
// in order, then + bias.
__device__ __forceinline__ bool np_spike(const float* __restrict__ xr,
                                         const float* __restrict__ wcol,
                                         size_t stride, float bias) {
  float g = 0.0f;
  for (int p0 = 0; p0 < D_MODEL; p0 += KC) {
    const int pe = min(p0 + KC, D_MODEL);
    float s = 0.0f;
    for (int d = p0; d < pe; ++d)
      s = fmaf(xr[d], wcol[(size_t)d * stride], s);
    g += s;
  }
  g += bias;
  return g > 1.0f;
}

// ---------------- x -> bf16 hi/lo split ----------------
__global__ void k_convx(const float* __restrict__ x, unsigned short* __restrict__ xh,
                        unsigned short* __restrict__ xl) {
  const int i = blockIdx.x * 256 + threadIdx.x;
  const float4 v = ((const float4*)x)[i];
  ushort4 h, l;
  h.x = f2bf(v.x); l.x = f2bf(v.x - bf2f(h.x));
  h.y = f2bf(v.y); l.y = f2bf(v.y - bf2f(h.y));
  h.z = f2bf(v.z); l.z = f2bf(v.z - bf2f(h.z));
  h.w = f2bf(v.w); l.w = f2bf(v.w - bf2f(h.w));
  ((ushort4*)xh)[i] = h;
  ((ushort4*)xl)[i] = l;
}

// ------- weight transpose+convert: in [R][C] f32 -> out [C][R] bf16 (hi[,lo]) ---
__global__ void k_convw(const float* __restrict__ in, unsigned short* __restrict__ hi,
                        unsigned short* __restrict__ lo, int R, int C) {
  const int e = blockIdx.y;
  const int ntx = C >> 6;
  const int tx = blockIdx.x % ntx;
  const int ty = blockIdx.x / ntx;
  const float* src = in + (size_t)e * R * C;
  const size_t obase = (size_t)e * R * C;
  __shared__ float t[64][65];
  const int tid = threadIdx.x;
#pragma unroll
  for (int it = 0; it < 4; ++it) {
    const int r = it * 16 + (tid >> 4);
    const float4 v = *(const float4*)(src + (size_t)(ty * 64 + r) * C + tx * 64 + (tid & 15) * 4);
    t[r][(tid & 15) * 4 + 0] = v.x;
    t[r][(tid & 15) * 4 + 1] = v.y;
    t[r][(tid & 15) * 4 + 2] = v.z;
    t[r][(tid & 15) * 4 + 3] = v.w;
  }
  __syncthreads();
#pragma unroll
  for (int it = 0; it < 2; ++it) {
    const int c = it * 32 + (tid >> 3);
    const int d0 = (tid & 7) * 8;
    s8v vh, vl;
#pragma unroll
    for (int i = 0; i < 8; ++i) {
      const float f = t[d0 + i][c];
      const unsigned short h = f2bf(f);
      vh[i] = (short)h;
      vl[i] = (short)f2bf(f - bf2f(h));
    }
    const size_t o = obase + (size_t)(tx * 64 + c) * R + ty * 64 + d0;
    *(s8v*)(hi + o) = vh;
    if (lo) *(s8v*)(lo + o) = vl;
  }
}

// ------- router: wave-per-token f64 logits; inner band -> exact np emu -------
__global__ void k_router(const float* __restrict__ x, const float* __restrict__ Wg,
                         const float* __restrict__ bg, int* __restrict__ top_e,
                         float* __restrict__ top_w) {
  const int t = (blockIdx.x * blockDim.x + threadIdx.x) >> 6;
  const int lane = threadIdx.x & 63;
  if (t >= NTOK) return;
  const float* xr = x + (size_t)t * D_MODEL;
  double acc[NEXP];
#pragma unroll
  for (int e = 0; e < NEXP; ++e) acc[e] = 0.0;
#pragma unroll
  for (int i = 0; i < D_MODEL / 64; ++i) {
    const int d = lane + 64 * i;
    const double xv = (double)xr[d];
    const float4 w0 = *(const float4*)(Wg + d * NEXP);
    const float4 w1 = *(const float4*)(Wg + d * NEXP + 4);
    acc[0] = fma(xv, (double)w0.x, acc[0]);
    acc[1] = fma(xv, (double)w0.y, acc[1]);
    acc[2] = fma(xv, (double)w0.z, acc[2]);
    acc[3] = fma(xv, (double)w0.w, acc[3]);
    acc[4] = fma(xv, (double)w1.x, acc[4]);
    acc[5] = fma(xv, (double)w1.y, acc[5]);
    acc[6] = fma(xv, (double)w1.z, acc[6]);
    acc[7] = fma(xv, (double)w1.w, acc[7]);
  }
#pragma unroll
  for (int e = 0; e < NEXP; ++e) {
#pragma unroll
    for (int s = 32; s > 0; s >>= 1) acc[e] += __shfl_down(acc[e], s);
  }
  if (lane == 0) {
    bool sp[NEXP];
#pragma unroll
    for (int e = 0; e < NEXP; ++e) {
      const double l = acc[e] + (double)bg[e];
      if (fabs(l - 1.0) < INNER)
        sp[e] = np_spike(xr, Wg + e, NEXP, bg[e]);
      else
        sp[e] = l > 1.0;
    }
    int e0 = -1, e1 = -1;
    for (int e = 0; e < NEXP; ++e) if (sp[e])  { if (e0 < 0) e0 = e; else if (e1 < 0) e1 = e; }
    for (int e = 0; e < NEXP; ++e) if (!sp[e]) { if (e0 < 0) e0 = e; else if (e1 < 0) e1 = e; }
    float w0v, w1v;
    if (sp[e0] == sp[e1]) { w0v = 0.5f; w1v = 0.5f; }
    else { w0v = 0.7310585786300049f; w1v = 0.2689414213699951f; }  // softmax([1,0])
    top_e[2 * t] = e0; top_e[2 * t + 1] = e1;
    top_w[2 * t] = w0v; top_w[2 * t + 1] = w1v;
  }
}

// ------- group pairs by expert, build tile table + per-XCD work tables -------
__global__ void k_group(const int* __restrict__ top_e,
                        int* __restrict__ pair_token, int* __restrict__ pair_expert,
                        int* __restrict__ tok_pair, int4* __restrict__ tile_tab,
                        int* __restrict__ meta,
                        int2* __restrict__ awork, int2* __restrict__ bwork) {
  __shared__ int cnt[NEXP], off[NEXP + 1], fill[NEXP], tstart[NEXP], tcnt[NEXP];
  const int tid = threadIdx.x;
  if (tid < NEXP) { cnt[tid] = 0; fill[tid] = 0; }
  __syncthreads();
  for (int i = tid; i < NPAIR; i += 256) atomicAdd(&cnt[top_e[i]], 1);
  __syncthreads();
  if (tid == 0) {
    off[0] = 0;
    for (int e = 0; e < NEXP; ++e) off[e + 1] = off[e] + cnt[e];
    int nt = 0;
    for (int e = 0; e < NEXP; ++e) {
      tstart[e] = nt;
      for (int s = 0; s < cnt[e]; s += TM) {
        tile_tab[nt] = make_int4(e, off[e] + s, min(TM, cnt[e] - s), 0);
        ++nt;
      }
      tcnt[e] = nt - tstart[e];
    }
    meta[0] = nt;   // ntiles
    meta[1] = 0;    // flag count
  }
  __syncthreads();
  for (int i = tid; i < 8 * AMAX; i += 256) awork[i] = make_int2(-1, 0);
  for (int i = tid; i < 8 * BMAX; i += 256) bwork[i] = make_int2(-1, 0);
  __syncthreads();
  // stage-A table: thread per (xcd, panel-rank); panels P = e*NBA+bn, XCD P%8.
  if (tid < 8 * NBA) {               // 176 threads
    const int x = tid & 7, i = tid >> 3;
    const int P = x + 8 * i;
    const int e = P / NBA, bn = P % NBA;
    int slot = 0;
    for (int j = 0; j < i; ++j) slot += tcnt[(x + 8 * j) / NBA];
    for (int m = 0; m < tcnt[e]; ++m)
      awork[x * AMAX + slot + m] = make_int2(tstart[e] + m, bn);
  }
  // stage-B table: panels P = e*NBB+bn (NBB=16), XCD P%8 (2 panels/expert/XCD).
  if (tid < 8 * NBB) {               // 128 threads
    const int x = tid & 7, i = tid >> 3;
    const int P = x + 8 * i;
    const int e = P / NBB, bn = P % NBB;
    int slot = 0;
    for (int j = 0; j < i; ++j) slot += tcnt[(x + 8 * j) / NBB];
    for (int m = 0; m < tcnt[e]; ++m)
      bwork[x * BMAX + slot + m] = make_int2(tstart[e] + m, bn);
  }
  for (int i = tid; i < NPAIR; i += 256) {
    const int e = top_e[i];
    const int pos = off[e] + atomicAdd(&fill[e], 1);
    pair_token[pos] = i >> 1;
    pair_expert[pos] = e;
    tok_pair[i] = pos;
  }
}

// ===== stage A: 64x128 tile, 32 KB LDS, glds staging =====
// LDS slots (16B each): xh[0,256) xl[256,512) gh[512,1024) gl[1024,1536) uh[1536,2048)
__launch_bounds__(256, 4)
__global__ void k_stage_a_bf(const unsigned short* __restrict__ xh,
                             const unsigned short* __restrict__ xl,
                             const unsigned short* __restrict__ wgh,
                             const unsigned short* __restrict__ wgl,
                             const unsigned short* __restrict__ wuh,
                             const float* __restrict__ bgate, const float* __restrict__ bup,
                             const int* __restrict__ pair_token,
                             const int4* __restrict__ tile_tab,
                             const int2* __restrict__ awork,
                             int* meta,
                             unsigned short* __restrict__ hbuf,
                             unsigned int* __restrict__ flags) {
  const int2 wk = awork[(blockIdx.x & 7) * AMAX + (blockIdx.x >> 3)];
  if (wk.x < 0) return;
  const int4 tt = tile_tab[wk.x];
  const int e = tt.x, row0 = tt.y, rows = tt.z;
  const int n0 = wk.y * 128;

  __shared__ __align__(16) unsigned short lds[2048 * 8];   // 32 KB

  const int tid = threadIdx.x;
  const int lane = tid & 63;
  const int wid = tid >> 6;
  const int fnb = wid * 2;   // wave's first n-frag (0..7 over 4 waves x 2)

  const unsigned short* p[8];
#pragma unroll
  for (int c = 0; c < 8; ++c) {
    const int idx = tid + 256 * c;
    if (idx < 512) {
      const int q = idx & 255;
      const int rn = ((q >> 6) << 4) + (q & 15);   // [0,64)
      const int j = (q & 63) >> 4;
      if (rn < rows) {
        const int tok = pair_token[row0 + rn];
        p[c] = ((idx >> 8) ? xl : xh) + (size_t)tok * D_MODEL + 8 * j;
      } else p[c] = xh;  // dummy valid address; rows >= `rows` never stored
    } else {
      const int b = (idx - 512) >> 9;
      const int q = (idx - 512) & 511;
      const int rn = ((q >> 6) << 4) + (q & 15);   // [0,128)
      const int j = (q & 63) >> 4;
      const unsigned short* base = (b == 0) ? wgh : (b == 1) ? wgl : wuh;
      p[c] = base + ((size_t)e * HID + n0 + rn) * D_MODEL + 8 * j;
    }
  }

  const f4v fz = {0.f, 0.f, 0.f, 0.f};
  f4v acc_g[4][2], acc_u[4][2];
#pragma unroll
  for (int m = 0; m < 4; ++m)
#pragma unroll
    for (int n = 0; n < 2; ++n) { acc_g[m][n] = fz; acc_u[m][n] = fz; }

  for (int k0 = 0; k0 < D_MODEL; k0 += 32) {
#pragma unroll
    for (int c = 0; c < 8; ++c)
      gld16(p[c] + k0, lds + (((c << 8) + (tid & 192)) << 3));
    __syncthreads();   // vmcnt(0) drain + barrier
    s8v bgh[2], bgl[2], buh[2];
#pragma unroll
    for (int n = 0; n < 2; ++n) {
      const int boff = ((fnb + n) * 64 + lane) * 8;
      bgh[n] = *(const s8v*)(lds + 4096 + boff);
      bgl[n] = *(const s8v*)(lds + 8192 + boff);
      buh[n] = *(const s8v*)(lds + 12288 + boff);
    }
#pragma unroll
    for (int m = 0; m < 4; ++m) {
      const s8v afh = *(const s8v*)(lds + (m * 64 + lane) * 8);
      const s8v afl = *(const s8v*)(lds + 2048 + (m * 64 + lane) * 8);
#pragma unroll
      for (int n = 0; n < 2; ++n) {
        acc_g[m][n] = __builtin_amdgcn_mfma_f32_16x16x32_bf16(afh, bgh[n], acc_g[m][n], 0, 0, 0);
        acc_g[m][n] = __builtin_amdgcn_mfma_f32_16x16x32_bf16(afh, bgl[n], acc_g[m][n], 0, 0, 0);
        acc_g[m][n] = __builtin_amdgcn_mfma_f32_16x16x32_bf16(afl, bgh[n], acc_g[m][n], 0, 0, 0);
        acc_u[m][n] = __builtin_amdgcn_mfma_f32_16x16x32_bf16(afh, buh[n], acc_u[m][n], 0, 0, 0);
      }
    }
    __syncthreads();   // readers done before next overwrite
  }

  const int lcol = lane & 15;
  const int lrow = (lane >> 4) * 4;
#pragma unroll
  for (int n = 0; n < 2; ++n) {
    const int col = n0 + (fnb + n) * 16 + lcol;
    const float bgv = bgate[e * HID + col];
    const float buv = bup[e * HID + col];
#pragma unroll
    for (int m = 0; m < 4; ++m) {
#pragma unroll
      for (int i = 0; i < 4; ++i) {
        const int r = m * 16 + lrow + i;
        if (r < rows) {
          const float g = acc_g[m][n][i] + bgv;
          const float u = acc_u[m][n][i] + buv;
          hbuf[(size_t)(row0 + r) * HID + col] = f2bf(g > 1.0f ? u : 0.0f);
          if (fabsf(g - 1.0f) < BAND) {
            const unsigned idx = atomicAdd((unsigned*)(meta + 1), 1u);
            if (idx < FLAGCAP) flags[idx] = ((unsigned)(row0 + r) << 16) | (unsigned)col;
          }
        }
      }
    }
  }
}

// ===== stage B: 64x64 tile, 16 KB LDS, glds staging =====
// LDS slots (16B each): h[0,512) wd[512,1024); BK=64 (j in [0,8))
__launch_bounds__(256, 4)
__global__ void k_stage_b_bf(const unsigned short* __restrict__ hbuf,
                             const unsigned short* __restrict__ wdh,
                             const int4* __restrict__ tile_tab,
                             const int2* __restrict__ bwork,
                             float* __restrict__ ybuf) {
  const int2 wk = bwork[(blockIdx.x & 7) * BMAX + (blockIdx.x >> 3)];
  if (wk.x < 0) return;
  const int4 tt = tile_tab[wk.x];
  const int e = tt.x, row0 = tt.y, rows = tt.z;
  const int n0 = wk.y * 64;

  __shared__ __align__(16) unsigned short lds[1024 * 8];   // 16 KB

  const int tid = threadIdx.x;
  const int lane = tid & 63;
  const int wid = tid >> 6;

  const unsigned short* p[4];
#pragma unroll
  for (int c = 0; c < 4; ++c) {
    const int idx = tid + 256 * c;
    const int arr = idx >> 9;
    const int q = idx & 511;
    const int rn = ((q >> 7) << 4) + (q & 15);   // [0,64)
    const int j = (q & 127) >> 4;                // [0,8)
    if (arr == 0) {
      p[c] = (rn < rows) ? (hbuf + (size_t)(row0 + rn) * HID + 8 * j) : hbuf;
    } else {
      p[c] = wdh + ((size_t)e * D_MODEL + n0 + rn) * HID + 8 * j;
    }
  }

  const f4v fz = {0.f, 0.f, 0.f, 0.f};
  f4v acc[4];
#pragma unroll
  for (int m = 0; m < 4; ++m) acc[m] = fz;

  for (int k0 = 0; k0 < HID; k0 += 64) {
#pragma unroll
    for (int c = 0; c < 4; ++c)
      gld16(p[c] + k0, lds + (((c << 8) + (tid & 192)) << 3));
    __syncthreads();
#pragma unroll
    for (int kk = 0; kk < 2; ++kk) {
      // wd region starts at slot 512 = ushort 4096 (round-14 bug: was 8192)
      const s8v bv = *(const s8v*)(lds + 4096 + (wid * 128 + kk * 64 + lane) * 8);
#pragma unroll
      for (int m = 0; m < 4; ++m) {
        const s8v af = *(const s8v*)(lds + (m * 128 + kk * 64 + lane) * 8);
        acc[m] = __builtin_amdgcn_mfma_f32_16x16x32_bf16(af, bv, acc[m], 0, 0, 0);
      }
    }
    __syncthreads();
  }

  const int lcol = lane & 15;
  const int lrow = (lane >> 4) * 4;
  const int col = n0 + wid * 16 + lcol;
#pragma unroll
  for (int m = 0; m < 4; ++m)
#pragma unroll
    for (int i = 0; i < 4; ++i) {
      const int r = m * 16 + lrow + i;
      if (r < rows)
        ybuf[(size_t)(row0 + r) * D_MODEL + col] = acc[m][i];
    }
}

// ---- patch: wave-per-flag f64 recompute; inner band -> exact np emulation ----
__global__ void k_patch(const float* __restrict__ x,
                        const float* __restrict__ Wgate, const float* __restrict__ bgate,
                        const float* __restrict__ Wup, const float* __restrict__ bup,
                        const int* __restrict__ pair_token, const int* __restrict__ pair_expert,
                        const int* __restrict__ meta, const unsigned* __restrict__ flags,
                        unsigned short* __restrict__ hbuf) {
  const int nw = (gridDim.x * blockDim.x) >> 6;
  const int w = (blockIdx.x * blockDim.x + threadIdx.x) >> 6;
  const int lane = threadIdx.x & 63;
  int n = meta[1];
  if (n > FLAGCAP) n = FLAGCAP;
  for (int f = w; f < n; f += nw) {
    const unsigned fl = flags[f];
    const int row = (int)(fl >> 16);
    const int col = (int)(fl & 0xFFFFu);
    const int tok = pair_token[row];
    const int e = pair_expert[row];
    const float* xr = x + (size_t)tok * D_MODEL;
    const float* wg = Wgate + (size_t)e * D_MODEL * HID + col;
    const float* wu = Wup + (size_t)e * D_MODEL * HID + col;
    double g = 0.0, u = 0.0;
#pragma unroll
    for (int i = 0; i < D_MODEL / 64; ++i) {
      const int d = lane + 64 * i;
      const double xv = (double)xr[d];
      g = fma(xv, (double)wg[(size_t)d * HID], g);
      u = fma(xv, (double)wu[(size_t)d * HID], u);
    }
#pragma unroll
    for (int s = 32; s > 0; s >>= 1) { g += __shfl_down(g, s); u += __shfl_down(u, s); }
    if (lane == 0) {
      g += (double)bgate[e * HID + col];
      u += (double)bup[e * HID + col];
      bool spike;
      if (fabs(g - 1.0) < INNER)
        spike = np_spike(xr, wg, HID, bgate[e * HID + col]);
      else
        spike = g > 1.0;
      hbuf[(size_t)row * HID + col] = f2bf(spike ? (float)u : 0.0f);
    }
  }
}

// ---------------- combine: out = w0*(y0+bd0) + w1*(y1+bd1) ----------------
__global__ void k_combine(const float* __restrict__ ybuf, const float* __restrict__ bdown,
                          const int* __restrict__ tok_pair, const int* __restrict__ top_e,
                          const float* __restrict__ top_w, float* __restrict__ out) {
  const int t = blockIdx.x;
  const int c = threadIdx.x;
  const int p0 = tok_pair[2 * t], p1 = tok_pair[2 * t + 1];
  const float w0 = top_w[2 * t], w1 = top_w[2 * t + 1];
  const int e0 = top_e[2 * t], e1 = top_e[2 * t + 1];
  const float4 y0 = ((const float4*)(ybuf + (size_t)p0 * D_MODEL))[c];
  const float4 y1 = ((const float4*)(ybuf + (size_t)p1 * D_MODEL))[c];
  const float4 b0 = ((const float4*)(bdown + (size_t)e0 * D_MODEL))[c];
  const float4 b1 = ((const float4*)(bdown + (size_t)e1 * D_MODEL))[c];
  float4 o;
  o.x = w0 * (y0.x + b0.x) + w1 * (y1.x + b1.x);
  o.y = w0 * (y0.y + b0.y) + w1 * (y1.y + b1.y);
  o.z = w0 * (y0.z + b0.z) + w1 * (y1.z + b1.z);
  o.w = w0 * (y0.w + b0.w) + w1 * (y1.w + b1.w);
  ((float4*)(out + (size_t)t * D_MODEL))[c] = o;
}

extern "C" void kernel_launch(void* const* d_in, const int* in_sizes, int n_in,
                              void* d_out, int out_size, void* d_ws, size_t ws_size,
                              hipStream_t stream) {
  const float* x     = (const float*)d_in[0];
  const float* Wg    = (const float*)d_in[1];
  const float* bg    = (const float*)d_in[2];
  const float* Wgate = (const float*)d_in[3];
  const float* bgate = (const float*)d_in[4];
  const float* Wup   = (const float*)d_in[5];
  const float* bup   = (const float*)d_in[6];
  const float* Wdown = (const float*)d_in[7];
  const float* bdown = (const float*)d_in[8];
  float* out = (float*)d_out;

  char* ws = (char*)d_ws;
  unsigned short* xh   = (unsigned short*)(ws + 0);
  unsigned short* xl   = (unsigned short*)(ws + 4194304);
  unsigned short* hbuf = (unsigned short*)(ws + 8388608);
  float* ybuf          = (float*)(ws + 31457280);
  int* top_e           = (int*)(ws + 48234496);
  float* top_w         = (float*)(ws + 48250880);
  int* pair_token      = (int*)(ws + 48267264);
  int* pair_expert     = (int*)(ws + 48283648);
  int* tok_pair        = (int*)(ws + 48300032);
  int4* tile_tab       = (int4*)(ws + 48316416);            // 2048 B (128 tiles)
  int* meta            = (int*)(ws + 48318464);             // 128
  unsigned* flags      = (unsigned*)(ws + 48318592);        // 131072 (FLAGCAP 32768)
  int2* awork          = (int2*)(ws + 48449664);            // 8*256*8 = 16384
  int2* bwork          = (int2*)(ws + 48466048);            // 8*160*8 = 10240
  // bf16 transposed weight panels (unchanged offsets)
  unsigned short* wgh  = (unsigned short*)(ws + 48590848);
  unsigned short* wgl  = (unsigned short*)(ws + 94728192);
  unsigned short* wuh  = (unsigned short*)(ws + 140865536);
  unsigned short* wdh  = (unsigned short*)(ws + 187002880);

  k_convx<<<dim3(NTOK * D_MODEL / 4 / 256), dim3(256), 0, stream>>>(x, xh, xl);
  k_router<<<dim3(NTOK / 4), dim3(256), 0, stream>>>(x, Wg, bg, top_e, top_w);
  k_group<<<dim3(1), dim3(256), 0, stream>>>(top_e, pair_token, pair_expert, tok_pair,
                                             tile_tab, meta, awork, bwork);
  k_convw<<<dim3(16 * 44, NEXP), dim3(256), 0, stream>>>(Wdown, wdh, nullptr, HID, D_MODEL);
  k_convw<<<dim3(44 * 16, NEXP), dim3(256), 0, stream>>>(Wup, wuh, nullptr, D_MODEL, HID);
  k_convw<<<dim3(44 * 16, NEXP), dim3(256), 0, stream>>>(Wgate, wgh, wgl, D_MODEL, HID);
  k_stage_a_bf<<<dim3(8 * AMAX), dim3(256), 0, stream>>>(
      xh, xl, wgh, wgl, wuh, bgate, bup, pair_token, tile_tab, awork, meta, hbuf, flags);
  k_patch<<<dim3(512), dim3(256), 0, stream>>>(x, Wgate, bgate, Wup, bup, pair_token,
                                               pair_expert, meta, flags, hbuf);
  k_stage_b_bf<<<dim3(8 * BMAX), dim3(256), 0, stream>>>(
      hbuf, wdh, tile_tab, bwork, ybuf);
  k_combine<<<dim3(NTOK), dim3(256), 0, stream>>>(ybuf, bdown, tok_pair, top_e, top_w, out);
}

// Round 16
// 497.989 us; speedup vs baseline: 1.1727x; 1.1727x over previous
//
#include <hip/hip_runtime.h>

// SpikingMoEFFN: top-2-of-8 spiking router + per-expert SpikingSwiGLU.
// Grouped-GEMM implementation. Spike decisions emulate the np reference's
// f32 BLAS accumulation (sgemm KC=384 panels; verified round 3) via bf16x3
// MFMA screen + f64/exact-emulation patch.
// Round 16: r13 geometry (128x128, lowest weight-re-read traffic) with
// COUNTED-vmcnt pipelining (T4): issue next tile's global_load_lds, then
// s_waitcnt vmcnt(N) for the CURRENT tile only + raw s_barrier — prefetch
// loads stay in flight across the barrier instead of the vmcnt(0) drain
// that serialized every prior variant's fetch stream.

#define D_MODEL 1024
#define HID     2816
#define NEXP    8
#define NTOK    2048
#define NPAIR   4096
#define TM      128
#define FLAGCAP  65536
#define KC      384
#define BAND    3e-4f
#define INNER   2e-5
#define NBA     22          // HID/128 n-panels (stage A)
#define NBB     8           // D_MODEL/128 n-panels (stage B)
#define AMAX    128         // per-XCD slot cap, stage A
#define BMAX    48          // per-XCD slot cap, stage B
#define ABUF    20480       // ushorts per stage-A LDS buffer (40 KB)
#define BBUF    16384       // ushorts per stage-B LDS buffer (32 KB)

typedef short s8v __attribute__((ext_vector_type(8)));
typedef float f4v __attribute__((ext_vector_type(4)));

__device__ __forceinline__ unsigned short f2bf(float f) {
  unsigned u = __float_as_uint(f);
  u += 0x7FFFu + ((u >> 16) & 1u);   // RTNE
  return (unsigned short)(u >> 16);
}
__device__ __forceinline__ float bf2f(unsigned short s) {
  return __uint_as_float(((unsigned)s) << 16);
}

// async global->LDS, 16B per lane; LDS dest = wave-uniform base + lane*16
__device__ __forceinline__ void gld16(const unsigned short* g, unsigned short* l) {
  __builtin_amdgcn_global_load_lds(
      (const __attribute__((address_space(1))) void*)g,
      (__attribute__((address_space(3))) void*)l, 16, 0, 0);
}

// Exact np-f32 gate emulation: seq FMA within KC=384 panels, panels added
// in order, then + bias.
__device__ __forceinline__ bool np_spike(const float* __restrict__ xr,
                                         const float* __restrict__ wcol,
                                         size_t stride, float bias) {
  float g = 0.0f;
  for (int p0 = 0; p0 < D_MODEL; p0 += KC) {
    const int pe = min(p0 + KC, D_MODEL);
    float s = 0.0f;
    for (int d = p0; d < pe; ++d)
      s = fmaf(xr[d], wcol[(size_t)d * stride], s);
    g += s;
  }
  g += bias;
  return g > 1.0f;
}

// ---------------- x -> bf16 hi/lo split ----------------
__global__ void k_convx(const float* __restrict__ x, unsigned short* __restrict__ xh,
                        unsigned short* __restrict__ xl) {
  const int i = blockIdx.x * 256 + threadIdx.x;
  const float4 v = ((const float4*)x)[i];
  ushort4 h, l;
  h.x = f2bf(v.x); l.x = f2bf(v.x - bf2f(h.x));
  h.y = f2bf(v.y); l.y = f2bf(v.y - bf2f(h.y));
  h.z = f2bf(v.z); l.z = f2bf(v.z - bf2f(h.z));
  h.w = f2bf(v.w); l.w = f2bf(v.w - bf2f(h.w));
  ((ushort4*)xh)[i] = h;
  ((ushort4*)xl)[i] = l;
}

// ------- weight transpose+convert: in [R][C] f32 -> out [C][R] bf16 (hi[,lo]) ---
__global__ void k_convw(const float* __restrict__ in, unsigned short* __restrict__ hi,
                        unsigned short* __restrict__ lo, int R, int C) {
  const int e = blockIdx.y;
  const int ntx = C >> 6;
  const int tx = blockIdx.x % ntx;
  const int ty = blockIdx.x / ntx;
  const float* src = in + (size_t)e * R * C;
  const size_t obase = (size_t)e * R * C;
  __shared__ float t[64][65];
  const int tid = threadIdx.x;
#pragma unroll
  for (int it = 0; it < 4; ++it) {
    const int r = it * 16 + (tid >> 4);
    const float4 v = *(const float4*)(src + (size_t)(ty * 64 + r) * C + tx * 64 + (tid & 15) * 4);
    t[r][(tid & 15) * 4 + 0] = v.x;
    t[r][(tid & 15) * 4 + 1] = v.y;
    t[r][(tid & 15) * 4 + 2] = v.z;
    t[r][(tid & 15) * 4 + 3] = v.w;
  }
  __syncthreads();
#pragma unroll
  for (int it = 0; it < 2; ++it) {
    const int c = it * 32 + (tid >> 3);
    const int d0 = (tid & 7) * 8;
    s8v vh, vl;
#pragma unroll
    for (int i = 0; i < 8; ++i) {
      const float f = t[d0 + i][c];
      const unsigned short h = f2bf(f);
      vh[i] = (short)h;
      vl[i] = (short)f2bf(f - bf2f(h));
    }
    const size_t o = obase + (size_t)(tx * 64 + c) * R + ty * 64 + d0;
    *(s8v*)(hi + o) = vh;
    if (lo) *(s8v*)(lo + o) = vl;
  }
}

// ------- router: wave-per-token f64 logits; inner band -> exact np emu -------
__global__ void k_router(const float* __restrict__ x, const float* __restrict__ Wg,
                         const float* __restrict__ bg, int* __restrict__ top_e,
                         float* __restrict__ top_w) {
  const int t = (blockIdx.x * blockDim.x + threadIdx.x) >> 6;
  const int lane = threadIdx.x & 63;
  if (t >= NTOK) return;
  const float* xr = x + (size_t)t * D_MODEL;
  double acc[NEXP];
#pragma unroll
  for (int e = 0; e < NEXP; ++e) acc[e] = 0.0;
#pragma unroll
  for (int i = 0; i < D_MODEL / 64; ++i) {
    const int d = lane + 64 * i;
    const double xv = (double)xr[d];
    const float4 w0 = *(const float4*)(Wg + d * NEXP);
    const float4 w1 = *(const float4*)(Wg + d * NEXP + 4);
    acc[0] = fma(xv, (double)w0.x, acc[0]);
    acc[1] = fma(xv, (double)w0.y, acc[1]);
    acc[2] = fma(xv, (double)w0.z, acc[2]);
    acc[3] = fma(xv, (double)w0.w, acc[3]);
    acc[4] = fma(xv, (double)w1.x, acc[4]);
    acc[5] = fma(xv, (double)w1.y, acc[5]);
    acc[6] = fma(xv, (double)w1.z, acc[6]);
    acc[7] = fma(xv, (double)w1.w, acc[7]);
  }
#pragma unroll
  for (int e = 0; e < NEXP; ++e) {
#pragma unroll
    for (int s = 32; s > 0; s >>= 1) acc[e] += __shfl_down(acc[e], s);
  }
  if (lane == 0) {
    bool sp[NEXP];
#pragma unroll
    for (int e = 0; e < NEXP; ++e) {
      const double l = acc[e] + (double)bg[e];
      if (fabs(l - 1.0) < INNER)
        sp[e] = np_spike(xr, Wg + e, NEXP, bg[e]);
      else
        sp[e] = l > 1.0;
    }
    int e0 = -1, e1 = -1;
    for (int e = 0; e < NEXP; ++e) if (sp[e])  { if (e0 < 0) e0 = e; else if (e1 < 0) e1 = e; }
    for (int e = 0; e < NEXP; ++e) if (!sp[e]) { if (e0 < 0) e0 = e; else if (e1 < 0) e1 = e; }
    float w0v, w1v;
    if (sp[e0] == sp[e1]) { w0v = 0.5f; w1v = 0.5f; }
    else { w0v = 0.7310585786300049f; w1v = 0.2689414213699951f; }  // softmax([1,0])
    top_e[2 * t] = e0; top_e[2 * t + 1] = e1;
    top_w[2 * t] = w0v; top_w[2 * t + 1] = w1v;
  }
}

// ------- group pairs by expert, build tile table + per-XCD work tables -------
__global__ void k_group(const int* __restrict__ top_e,
                        int* __restrict__ pair_token, int* __restrict__ pair_expert,
                        int* __restrict__ tok_pair, int4* __restrict__ tile_tab,
                        int* __restrict__ meta,
                        int2* __restrict__ awork, int2* __restrict__ bwork) {
  __shared__ int cnt[NEXP], off[NEXP + 1], fill[NEXP], tstart[NEXP], tcnt[NEXP];
  const int tid = threadIdx.x;
  if (tid < NEXP) { cnt[tid] = 0; fill[tid] = 0; }
  __syncthreads();
  for (int i = tid; i < NPAIR; i += 256) atomicAdd(&cnt[top_e[i]], 1);
  __syncthreads();
  if (tid == 0) {
    off[0] = 0;
    for (int e = 0; e < NEXP; ++e) off[e + 1] = off[e] + cnt[e];
    int nt = 0;
    for (int e = 0; e < NEXP; ++e) {
      tstart[e] = nt;
      for (int s = 0; s < cnt[e]; s += TM) {
        tile_tab[nt] = make_int4(e, off[e] + s, min(TM, cnt[e] - s), 0);
        ++nt;
      }
      tcnt[e] = nt - tstart[e];
    }
    meta[0] = nt;   // ntiles
    meta[1] = 0;    // flag count
  }
  __syncthreads();
  for (int i = tid; i < 8 * AMAX; i += 256) awork[i] = make_int2(-1, 0);
  for (int i = tid; i < 8 * BMAX; i += 256) bwork[i] = make_int2(-1, 0);
  __syncthreads();
  // stage-A table: thread per (xcd, panel-rank); panels P = e*NBA+bn, XCD P%8.
  if (tid < 8 * NBA) {               // 176 threads
    const int x = tid & 7, i = tid >> 3;
    const int P = x + 8 * i;
    const int e = P / NBA, bn = P % NBA;
    int slot = 0;
    for (int j = 0; j < i; ++j) slot += tcnt[(x + 8 * j) / NBA];
    for (int m = 0; m < tcnt[e]; ++m)
      awork[x * AMAX + slot + m] = make_int2(tstart[e] + m, bn);
  }
  // stage-B table: XCD x owns n-panel bn = x for all experts.
  if (tid >= 192 && tid < 192 + 8 * NBB) {   // 64 threads
    const int t2 = tid - 192;
    const int x = t2 & 7, i = t2 >> 3;
    const int P = x + 8 * i;
    const int e = P / NBB, bn = P % NBB;
    int slot = 0;
    for (int j = 0; j < i; ++j) slot += tcnt[(x + 8 * j) / NBB];
    for (int m = 0; m < tcnt[e]; ++m)
      bwork[x * BMAX + slot + m] = make_int2(tstart[e] + m, bn);
  }
  for (int i = tid; i < NPAIR; i += 256) {
    const int e = top_e[i];
    const int pos = off[e] + atomicAdd(&fill[e], 1);
    pair_token[pos] = i >> 1;
    pair_expert[pos] = e;
    tok_pair[i] = pos;
  }
}

// ===== stage A: 128x128, glds dbuf + COUNTED vmcnt pipeline =====
__launch_bounds__(256, 2)
__global__ void k_stage_a_bf(const unsigned short* __restrict__ xh,
                             const unsigned short* __restrict__ xl,
                             const unsigned short* __restrict__ wgh,
                             const unsigned short* __restrict__ wgl,
                             const unsigned short* __restrict__ wuh,
                             const float* __restrict__ bgate, const float* __restrict__ bup,
                             const int* __restrict__ pair_token,
                             const int4* __restrict__ tile_tab,
                             const int2* __restrict__ awork,
                             int* meta,
                             unsigned short* __restrict__ hbuf,
                             unsigned int* __restrict__ flags) {
  const int2 wk = awork[(blockIdx.x & 7) * AMAX + (blockIdx.x >> 3)];
  if (wk.x < 0) return;
  const int4 tt = tile_tab[wk.x];
  const int e = tt.x, row0 = tt.y, rows = tt.z;
  const int n0 = wk.y * 128;

  __shared__ __align__(16) unsigned short lds[2 * ABUF];   // 80 KB

  const int tid = threadIdx.x;
  const int lane = tid & 63;
  const int wid = tid >> 6;
  const int wmb = (wid >> 1) * 4;
  const int wnb = (wid & 1) * 4;
  const int sbase = ((tid & 192)) << 3;   // wave-uniform chunk base

  const unsigned short* p[10];
#pragma unroll
  for (int c = 0; c < 10; ++c) {
    const int idx = tid + 256 * c;
    const int arr = idx >> 9;
    const int q = idx & 511;
    const int rn = ((q >> 6) << 4) + (q & 15);
    const int j = (q & 63) >> 4;
    if (arr < 2) {
      if (rn < rows) {
        const int tok = pair_token[row0 + rn];
        p[c] = (arr ? xl : xh) + (size_t)tok * D_MODEL + 8 * j;
      } else p[c] = xh;  // dummy valid address; rows >= `rows` never stored
    } else {
      const unsigned short* base = (arr == 2) ? wgh : (arr == 3) ? wgl : wuh;
      p[c] = base + ((size_t)e * HID + n0 + rn) * D_MODEL + 8 * j;
    }
  }

  const f4v fz = {0.f, 0.f, 0.f, 0.f};
  f4v acc_g[4][4], acc_u[4][4];
#pragma unroll
  for (int m = 0; m < 4; ++m)
#pragma unroll
    for (int n = 0; n < 4; ++n) { acc_g[m][n] = fz; acc_u[m][n] = fz; }

  // prologue: issue tile0 into buffer 0 (no wait — first loop iter waits)
#pragma unroll
  for (int c = 0; c < 10; ++c)
    gld16(p[c], lds + ((c << 11) + sbase));

  int cur = 0;
  for (int k0 = 0; k0 < D_MODEL; k0 += 32) {
    unsigned short* const L = lds + (cur ? ABUF : 0);
    if (k0 + 32 < D_MODEL) {
      unsigned short* const Lp = lds + (cur ? 0 : ABUF);
#pragma unroll
      for (int c = 0; c < 10; ++c)
        gld16(p[c] + k0 + 32, Lp + ((c << 11) + sbase));
      // wait for CURRENT tile's 10 loads only; next tile's stay in flight
      asm volatile("s_waitcnt vmcnt(10)" ::: "memory");
    } else {
      asm volatile("s_waitcnt vmcnt(0)" ::: "memory");
    }
    __builtin_amdgcn_s_barrier();   // all waves' current-tile loads landed
    s8v afh[4], afl[4];
#pragma unroll
    for (int m = 0; m < 4; ++m) {
      afh[m] = *(const s8v*)(L + ((wmb + m) * 64 + lane) * 8);
      afl[m] = *(const s8v*)(L + 4096 + ((wmb + m) * 64 + lane) * 8);
    }
#pragma unroll
    for (int n = 0; n < 4; ++n) {
      const int boff = ((wnb + n) * 64 + lane) * 8;
      const s8v bgh = *(const s8v*)(L + 8192 + boff);
      const s8v bgl = *(const s8v*)(L + 12288 + boff);
      const s8v buh = *(const s8v*)(L + 16384 + boff);
#pragma unroll
      for (int m = 0; m < 4; ++m)
        acc_g[m][n] = __builtin_amdgcn_mfma_f32_16x16x32_bf16(afh[m], bgh, acc_g[m][n], 0, 0, 0);
#pragma unroll
      for (int m = 0; m < 4; ++m)
        acc_g[m][n] = __builtin_amdgcn_mfma_f32_16x16x32_bf16(afh[m], bgl, acc_g[m][n], 0, 0, 0);
#pragma unroll
      for (int m = 0; m < 4; ++m)
        acc_g[m][n] = __builtin_amdgcn_mfma_f32_16x16x32_bf16(afl[m], bgh, acc_g[m][n], 0, 0, 0);
#pragma unroll
      for (int m = 0; m < 4; ++m)
        acc_u[m][n] = __builtin_amdgcn_mfma_f32_16x16x32_bf16(afh[m], buh, acc_u[m][n], 0, 0, 0);
    }
    __builtin_amdgcn_s_barrier();   // readers done before buffer reuse
    cur ^= 1;
  }

  const int lcol = lane & 15;
  const int lrow = (lane >> 4) * 4;
#pragma unroll
  for (int n = 0; n < 4; ++n) {
    const int col = n0 + (wnb + n) * 16 + lcol;
    const float bgv = bgate[e * HID + col];
    const float buv = bup[e * HID + col];
#pragma unroll
    for (int m = 0; m < 4; ++m) {
#pragma unroll
      for (int i = 0; i < 4; ++i) {
        const int r = (wmb + m) * 16 + lrow + i;
        if (r < rows) {
          const float g = acc_g[m][n][i] + bgv;
          const float u = acc_u[m][n][i] + buv;
          hbuf[(size_t)(row0 + r) * HID + col] = f2bf(g > 1.0f ? u : 0.0f);
          if (fabsf(g - 1.0f) < BAND) {
            const unsigned idx = atomicAdd((unsigned*)(meta + 1), 1u);
            if (idx < FLAGCAP) flags[idx] = ((unsigned)(row0 + r) << 16) | (unsigned)col;
          }
        }
      }
    }
  }
}

// ===== stage B: 128x128, glds dbuf + COUNTED vmcnt pipeline =====
__launch_bounds__(256, 2)
__global__ void k_stage_b_bf(const unsigned short* __restrict__ hbuf,
                             const unsigned short* __restrict__ wdh,
                             const int4* __restrict__ tile_tab,
                             const int2* __restrict__ bwork,
                             float* __restrict__ ybuf) {
  const int2 wk = bwork[(blockIdx.x & 7) * BMAX + (blockIdx.x >> 3)];
  if (wk.x < 0) return;
  const int4 tt = tile_tab[wk.x];
  const int e = tt.x, row0 = tt.y, rows = tt.z;
  const int n0 = wk.y * 128;

  __shared__ __align__(16) unsigned short lds[2 * BBUF];   // 64 KB

  const int tid = threadIdx.x;
  const int lane = tid & 63;
  const int wid = tid >> 6;
  const int wmb = (wid >> 1) * 4;
  const int wnb = (wid & 1) * 4;
  const int sbase = ((tid & 192)) << 3;

  const unsigned short* p[8];
#pragma unroll
  for (int c = 0; c < 8; ++c) {
    const int idx = tid + 256 * c;
    const int arr = idx >> 10;
    const int q = idx & 1023;
    const int rn = ((q >> 7) << 4) + (q & 15);
    const int j = (q & 127) >> 4;
    if (arr == 0) {
      p[c] = (rn < rows) ? (hbuf + (size_t)(row0 + rn) * HID + 8 * j) : hbuf;
    } else {
      p[c] = wdh + ((size_t)e * D_MODEL + n0 + rn) * HID + 8 * j;
    }
  }

  const f4v fz = {0.f, 0.f, 0.f, 0.f};
  f4v acc[4][4];
#pragma unroll
  for (int m = 0; m < 4; ++m)
#pragma unroll
    for (int n = 0; n < 4; ++n) acc[m][n] = fz;

#pragma unroll
  for (int c = 0; c < 8; ++c)
    gld16(p[c], lds + ((c << 11) + sbase));

  int cur = 0;
  for (int k0 = 0; k0 < HID; k0 += 64) {
    unsigned short* const L = lds + (cur ? BBUF : 0);
    if (k0 + 64 < HID) {
      unsigned short* const Lp = lds + (cur ? 0 : BBUF);
#pragma unroll
      for (int c = 0; c < 8; ++c)
        gld16(p[c] + k0 + 64, Lp + ((c << 11) + sbase));
      asm volatile("s_waitcnt vmcnt(8)" ::: "memory");
    } else {
      asm volatile("s_waitcnt vmcnt(0)" ::: "memory");
    }
    __builtin_amdgcn_s_barrier();
#pragma unroll
    for (int kk = 0; kk < 2; ++kk) {
      s8v af[4];
#pragma unroll
      for (int m = 0; m < 4; ++m)
        af[m] = *(const s8v*)(L + ((wmb + m) * 128 + kk * 64 + lane) * 8);
#pragma unroll
      for (int n = 0; n < 4; ++n) {
        const s8v bv = *(const s8v*)(L + 8192 + ((wnb + n) * 128 + kk * 64 + lane) * 8);
#pragma unroll
        for (int m = 0; m < 4; ++m)
          acc[m][n] = __builtin_amdgcn_mfma_f32_16x16x32_bf16(af[m], bv, acc[m][n], 0, 0, 0);
      }
    }
    __builtin_amdgcn_s_barrier();
    cur ^= 1;
  }

  const int lcol = lane & 15;
  const int lrow = (lane >> 4) * 4;
#pragma unroll
  for (int m = 0; m < 4; ++m)
#pragma unroll
    for (int i = 0; i < 4; ++i) {
      const int r = (wmb + m) * 16 + lrow + i;
      if (r < rows) {
#pragma unroll
        for (int n = 0; n < 4; ++n) {
          const int col = n0 + (wnb + n) * 16 + lcol;
          ybuf[(size_t)(row0 + r) * D_MODEL + col] = acc[m][n][i];
        }
      }
    }
}

// ---- patch: wave-per-flag f64 recompute; inner band -> exact np emulation ----
__global__ void k_patch(const float* __restrict__ x,
                        const float* __restrict__ Wgate, const float* __restrict__ bgate,
                        const float* __restrict__ Wup, const float* __restrict__ bup,
                        const int* __restrict__ pair_token, const int* __restrict__ pair_expert,
                        const int* __restrict__ meta, const unsigned* __restrict__ flags,
                        unsigned short* __restrict__ hbuf) {
  const int nw = (gridDim.x * blockDim.x) >> 6;
  const int w = (blockIdx.x * blockDim.x + threadIdx.x) >> 6;
  const int lane = threadIdx.x & 63;
  int n = meta[1];
  if (n > FLAGCAP) n = FLAGCAP;
  for (int f = w; f < n; f += nw) {
    const unsigned fl = flags[f];
    const int row = (int)(fl >> 16);
    const int col = (int)(fl & 0xFFFFu);
    const int tok = pair_token[row];
    const int e = pair_expert[row];
    const float* xr = x + (size_t)tok * D_MODEL;
    const float* wg = Wgate + (size_t)e * D_MODEL * HID + col;
    const float* wu = Wup + (size_t)e * D_MODEL * HID + col;
    double g = 0.0, u = 0.0;
#pragma unroll
    for (int i = 0; i < D_MODEL / 64; ++i) {
      const int d = lane + 64 * i;
      const double xv = (double)xr[d];
      g = fma(xv, (double)wg[(size_t)d * HID], g);
      u = fma(xv, (double)wu[(size_t)d * HID], u);
    }
#pragma unroll
    for (int s = 32; s > 0; s >>= 1) { g += __shfl_down(g, s); u += __shfl_down(u, s); }
    if (lane == 0) {
      g += (double)bgate[e * HID + col];
      u += (double)bup[e * HID + col];
      bool spike;
      if (fabs(g - 1.0) < INNER)
        spike = np_spike(xr, wg, HID, bgate[e * HID + col]);
      else
        spike = g > 1.0;
      hbuf[(size_t)row * HID + col] = f2bf(spike ? (float)u : 0.0f);
    }
  }
}

// ---------------- combine: out = w0*(y0+bd0) + w1*(y1+bd1) ----------------
__global__ void k_combine(const float* __restrict__ ybuf, const float* __restrict__ bdown,
                          const int* __restrict__ tok_pair, const int* __restrict__ top_e,
                          const float* __restrict__ top_w, float* __restrict__ out) {
  const int t = blockIdx.x;
  const int c = threadIdx.x;
  const int p0 = tok_pair[2 * t], p1 = tok_pair[2 * t + 1];
  const float w0 = top_w[2 * t], w1 = top_w[2 * t + 1];
  const int e0 = top_e[2 * t], e1 = top_e[2 * t + 1];
  const float4 y0 = ((const float4*)(ybuf + (size_t)p0 * D_MODEL))[c];
  const float4 y1 = ((const float4*)(ybuf + (size_t)p1 * D_MODEL))[c];
  const float4 b0 = ((const float4*)(bdown + (size_t)e0 * D_MODEL))[c];
  const float4 b1 = ((const float4*)(bdown + (size_t)e1 * D_MODEL))[c];
  float4 o;
  o.x = w0 * (y0.x + b0.x) + w1 * (y1.x + b1.x);
  o.y = w0 * (y0.y + b0.y) + w1 * (y1.y + b1.y);
  o.z = w0 * (y0.z + b0.z) + w1 * (y1.z + b1.z);
  o.w = w0 * (y0.w + b0.w) + w1 * (y1.w + b1.w);
  ((float4*)(out + (size_t)t * D_MODEL))[c] = o;
}

extern "C" void kernel_launch(void* const* d_in, const int* in_sizes, int n_in,
                              void* d_out, int out_size, void* d_ws, size_t ws_size,
                              hipStream_t stream) {
  const float* x     = (const float*)d_in[0];
  const float* Wg    = (const float*)d_in[1];
  const float* bg    = (const float*)d_in[2];
  const float* Wgate = (const float*)d_in[3];
  const float* bgate = (const float*)d_in[4];
  const float* Wup   = (const float*)d_in[5];
  const float* bup   = (const float*)d_in[6];
  const float* Wdown = (const float*)d_in[7];
  const float* bdown = (const float*)d_in[8];
  float* out = (float*)d_out;

  char* ws = (char*)d_ws;
  unsigned short* xh   = (unsigned short*)(ws + 0);
  unsigned short* xl   = (unsigned short*)(ws + 4194304);
  unsigned short* hbuf = (unsigned short*)(ws + 8388608);
  float* ybuf          = (float*)(ws + 31457280);
  int* top_e           = (int*)(ws + 48234496);
  float* top_w         = (float*)(ws + 48250880);
  int* pair_token      = (int*)(ws + 48267264);
  int* pair_expert     = (int*)(ws + 48283648);
  int* tok_pair        = (int*)(ws + 48300032);
  int4* tile_tab       = (int4*)(ws + 48316416);
  int* meta            = (int*)(ws + 48317184);
  unsigned* flags      = (unsigned*)(ws + 48317440);
  int2* awork          = (int2*)(ws + 48579584);             // 8*128*8 = 8192
  int2* bwork          = (int2*)(ws + 48587776);             // 8*48*8  = 3072
  // bf16 transposed weight panels
  unsigned short* wgh  = (unsigned short*)(ws + 48590848);
  unsigned short* wgl  = (unsigned short*)(ws + 94728192);
  unsigned short* wuh  = (unsigned short*)(ws + 140865536);
  unsigned short* wdh  = (unsigned short*)(ws + 187002880);

  k_convx<<<dim3(NTOK * D_MODEL / 4 / 256), dim3(256), 0, stream>>>(x, xh, xl);
  k_router<<<dim3(NTOK / 4), dim3(256), 0, stream>>>(x, Wg, bg, top_e, top_w);
  k_group<<<dim3(1), dim3(256), 0, stream>>>(top_e, pair_token, pair_expert, tok_pair,
                                             tile_tab, meta, awork, bwork);
  k_convw<<<dim3(16 * 44, NEXP), dim3(256), 0, stream>>>(Wdown, wdh, nullptr, HID, D_MODEL);
  k_convw<<<dim3(44 * 16, NEXP), dim3(256), 0, stream>>>(Wup, wuh, nullptr, D_MODEL, HID);
  k_convw<<<dim3(44 * 16, NEXP), dim3(256), 0, stream>>>(Wgate, wgh, wgl, D_MODEL, HID);
  k_stage_a_bf<<<dim3(8 * AMAX), dim3(256), 0, stream>>>(
      xh, xl, wgh, wgl, wuh, bgate, bup, pair_token, tile_tab, awork, meta, hbuf, flags);
  k_patch<<<dim3(512), dim3(256), 0, stream>>>(x, Wgate, bgate, Wup, bup, pair_token,
                                               pair_expert, meta, flags, hbuf);
  k_stage_b_bf<<<dim3(8 * BMAX), dim3(256), 0, stream>>>(
      hbuf, wdh, tile_tab, bwork, ybuf);
  k_combine<<<dim3(NTOK), dim3(256), 0, stream>>>(ybuf, bdown, tok_pair, top_e, top_w, out);
}